// Round 10
// baseline (180.282 us; speedup 1.0000x reference)
//
#include <hip/hip_runtime.h>
#include <stdint.h>

#define NN 100000     // nodes
#define NE 640000     // edges
#define DD 128        // features
#define BN_EPS 1e-5f
#define NB 391        // scan blocks: 391*256 = 100096 >= NN
#define NROWPAD 100096
#define NTILE 782     // 128-row tiles: 782*128 = 100096
#define GGRID 512     // gemm grid (2 blocks/CU)

// merged setup-kernel block ranges
#define SETUP_PREPX_BLOCKS 6256   // NROWPAD*16/256
#define SETUP_PREPW_BLOCKS 128
#define SETUP_HIST_BLOCKS  2500

typedef __attribute__((ext_vector_type(8)))  short bf16x8;
typedef __attribute__((ext_vector_type(16))) short bf16x16;
typedef __attribute__((ext_vector_type(4)))  float f32x4;

static __device__ __forceinline__ float bf2f(unsigned short s) {
  return __uint_as_float(((unsigned)s) << 16);
}
static __device__ __forceinline__ unsigned short f2bf(float f) {
  unsigned u = __float_as_uint(f);
  u += 0x7FFFu + ((u >> 16) & 1u);   // RNE
  return (unsigned short)(u >> 16);
}

// ---- 0. zero deg ---------------------------------------------------------
__global__ __launch_bounds__(1024) void k_zero(int* __restrict__ deg)
{
  int i = blockIdx.x * 1024 + threadIdx.x;
  if (i < NROWPAD) deg[i] = 0;
}

// ---- 1. merged setup: prepx (incl. pad-row zero) + prepw + hist ----------
__global__ __launch_bounds__(256) void k_setup(
    const float* __restrict__ x,
    const float* __restrict__ Wl, const float* __restrict__ Wr,
    const int* __restrict__ ei,
    unsigned short* __restrict__ abuf, unsigned short* __restrict__ wbf,
    int* __restrict__ deg)
{
  int b = blockIdx.x;
  if (b < SETUP_PREPX_BLOCKS) {
    // abuf[row][128+j] = bf16(relu(x[row][j])); pad rows zero BOTH halves
    int i = b * 256 + threadIdx.x;      // 0 .. NROWPAD*16-1
    int row = i >> 4, cj = i & 15;
    if (row < NN) {
      const float* xp = x + (long)row * DD + cj * 8;
      float tmp[8];
      *(float4*)(tmp)     = *(const float4*)(xp);
      *(float4*)(tmp + 4) = *(const float4*)(xp + 4);
      bf16x8 o;
#pragma unroll
      for (int e = 0; e < 8; ++e) o[e] = (short)f2bf(fmaxf(tmp[e], 0.f));
      *(bf16x8*)(abuf + (long)row * 256 + DD + cj * 8) = o;
    } else {                            // rows NN..NROWPAD-1: zero fill
      bf16x8 z = {};
      *(bf16x8*)(abuf + (long)row * 256 + cj * 8) = z;        // agg half
      *(bf16x8*)(abuf + (long)row * 256 + DD + cj * 8) = z;   // x half
    }
  } else if (b < SETUP_PREPX_BLOCKS + SETUP_PREPW_BLOCKS) {
    // wbf[col][0..255] = [Wl[col][:] | Wr[col][:]] as bf16
    int i = (b - SETUP_PREPX_BLOCKS) * 256 + threadIdx.x;
    int col = i >> 8, k = i & 255;
    float v = (k < DD) ? Wl[col * DD + k] : Wr[col * DD + (k - DD)];
    wbf[i] = f2bf(v);
  } else {
    // degree histogram
    int e = (b - SETUP_PREPX_BLOCKS - SETUP_PREPW_BLOCKS) * 256 + threadIdx.x;
    if (e < NE) atomicAdd(deg + ei[NE + e], 1);
  }
}

// ---- 4. block sums -------------------------------------------------------
__global__ __launch_bounds__(256) void k_scan1(const int* __restrict__ deg,
                                               int* __restrict__ bsum)
{
  __shared__ int sc[256];
  int t = threadIdx.x;
  sc[t] = deg[blockIdx.x * 256 + t];
  __syncthreads();
  for (int s = 128; s > 0; s >>= 1) {
    if (t < s) sc[t] += sc[t + s];
    __syncthreads();
  }
  if (t == 0) bsum[blockIdx.x] = sc[0];
}

// ---- 5. exclusive scan of block sums ------------------------------------
__global__ __launch_bounds__(512) void k_scan2(const int* __restrict__ bsum,
                                               int* __restrict__ boff)
{
  __shared__ int sc[512];
  int t = threadIdx.x;
  int v = (t < NB) ? bsum[t] : 0;
  sc[t] = v;
  __syncthreads();
  for (int s = 1; s < 512; s <<= 1) {
    int add = (t >= s) ? sc[t - s] : 0;
    __syncthreads();
    sc[t] += add;
    __syncthreads();
  }
  if (t < NB) boff[t] = sc[t] - v;
}

// ---- 6. per-element exclusive scan -> offs; deg becomes fill-cursor ------
__global__ __launch_bounds__(256) void k_scan3(int* __restrict__ deg,
                                               const int* __restrict__ boff,
                                               int* __restrict__ offs)
{
  __shared__ int sc[256];
  int t = threadIdx.x;
  int i = blockIdx.x * 256 + t;
  int v = deg[i];
  sc[t] = v;
  __syncthreads();
  for (int s = 1; s < 256; s <<= 1) {
    int add = (t >= s) ? sc[t - s] : 0;
    __syncthreads();
    sc[t] += add;
    __syncthreads();
  }
  int excl = sc[t] - v + boff[blockIdx.x];
  offs[i] = excl;
  deg[i]  = excl;
}

// ---- 7. fill CSR ---------------------------------------------------------
__global__ __launch_bounds__(256) void k_fill(const int* __restrict__ ei,
                                              int* __restrict__ cursor,
                                              int* __restrict__ esrc)
{
  int e = blockIdx.x * 256 + threadIdx.x;
  if (e >= NE) return;
  int pos = atomicAdd(cursor + ei[NE + e], 1);
  esrc[pos] = ei[e];
}

// ---- 8. gather-aggregate: abuf[dst][0..127] = bf16(mean(relu_x_bf16[src]))
// R9: 8 edge-slots x 8 feature-lanes (was 4x16). Each lane reads 2 x 16B
// of its slot's row -> 8 edges per iteration, iters = ceil(deg/8) = ONE
// latency round-trip for typical deg ~6.4 (was 2), and 2 loads in flight
// per iter (x unroll 2 = 4). Lanes past the edge count hold src=NN
// (zeroed pad row) -> adds 0, branch-free. shfl_xor(8,16,32) reduce;
// slot 0 (8 lanes x 32B) packs+stores the 256B mean row.
__global__ __launch_bounds__(256) void k_agg(const int* __restrict__ offs,
                                             const int* __restrict__ esrc,
                                             unsigned short* __restrict__ abuf)
{
  int dst = blockIdx.x * 4 + (threadIdx.x >> 6);
  if (dst >= NN) return;
  int lane = threadIdx.x & 63;
  int slot = lane >> 3;      // 0..7 edge slot
  int fl   = lane & 7;       // feature lane: feats fl*16 .. fl*16+15
  int off = offs[dst], end = offs[dst + 1];
  int deg = end - off;
  float acc[16];
#pragma unroll
  for (int e = 0; e < 16; ++e) acc[e] = 0.f;

  for (int base = off; base < end; base += 64) {
    int m = end - base; if (m > 64) m = 64;
    int mysrc = (base + lane < end) ? esrc[base + lane] : NN;  // NN = zero pad row
    int iters = (m + 7) >> 3;
#pragma unroll 2
    for (int i = 0; i < iters; ++i) {
      int src = __shfl(mysrc, i * 8 + slot);   // i*8+slot <= 63
      const unsigned short* p = abuf + (long)src * 256 + DD + fl * 16;
      bf16x8 w0 = *(const bf16x8*)(p);
      bf16x8 w1 = *(const bf16x8*)(p + 8);
#pragma unroll
      for (int e = 0; e < 8; ++e) acc[e]     += bf2f((unsigned short)w0[e]);
#pragma unroll
      for (int e = 0; e < 8; ++e) acc[8 + e] += bf2f((unsigned short)w1[e]);
    }
  }

#pragma unroll
  for (int e = 0; e < 16; ++e) {
    acc[e] += __shfl_xor(acc[e], 8);
    acc[e] += __shfl_xor(acc[e], 16);
    acc[e] += __shfl_xor(acc[e], 32);
  }
  if (slot == 0) {
    float rinv = (deg > 0) ? 1.0f / (float)deg : 0.f;
    bf16x16 o;
#pragma unroll
    for (int e = 0; e < 16; ++e) o[e] = (short)f2bf(acc[e] * rinv);
    *(bf16x16*)(abuf + (long)dst * 256 + fl * 16) = o;   // 8 lanes x 32B = 256B
  }
}

// ======== streaming GEMM core (barrier-free per wave) =====================
// Block: 512 thr = 8 waves. B (= wbf, 128x256 bf16 = 64KB) staged once in
// LDS with XOR-swizzle byte ^= (col&7)<<4. Each wave owns a 16-row strip
// per tile; A-fragments load DIRECTLY from global (wave-wide 16B load =
// 16 full 64B lines). No A-LDS, no barriers in the tile loop.
// REGISTER BUDGET: (512,2) caps VGPR at 128 (2 blocks/CU, LDS-bound).
// R9: A-load unroll 2 -> 4 (4 frags in flight; revert if spill signature
// -- WRITE_SIZE inflation -- reappears).
#define GEMM_STAGE_B() \
  _Pragma("unroll") \
  for (int j = 0; j < 8; ++j) { \
    int id = j * 512 + t, col = id >> 5, seg = id & 31; \
    uint4 v = *(const uint4*)(wbf + col * 256 + seg * 8); \
    int byte = (col << 9) + (seg << 4); byte ^= (col & 7) << 4; \
    *(uint4*)((char*)blds + byte) = v; \
  } \
  __syncthreads();

#define GEMM_TILE_COMPUTE(rb) \
  { const unsigned short* ap = abuf + (long)((rb) + c15) * 256 + kg * 8; \
    _Pragma("unroll 4") \
    for (int ks = 0; ks < 8; ++ks) { \
      bf16x8 a = *(const bf16x8*)(ap + ks * 32); \
      _Pragma("unroll") \
      for (int ct = 0; ct < 8; ++ct) { \
        int byte = ((ct * 16 + c15) << 9) + (ks << 6) + (kg << 4); \
        byte ^= (c15 & 7) << 4; \
        bf16x8 b = *(const bf16x8*)((const char*)blds + byte); \
        acc[ct] = __builtin_amdgcn_mfma_f32_16x16x32_bf16(a, b, acc[ct], 0, 0, 0); \
      } \
    } }

// ---- 9a. GEMM pass 1: RAW column stats (no bias, no row guard) -----------
__global__ __launch_bounds__(512, 2) void k_gemm1(
    const unsigned short* __restrict__ abuf,
    const unsigned short* __restrict__ wbf,
    float* __restrict__ partials)
{
  __shared__ __align__(16) unsigned short blds[32768];   // 64KB B
  const int t = threadIdx.x;
  const int lane = t & 63, wv = t >> 6;
  const int c15 = lane & 15, kg = lane >> 4;

  GEMM_STAGE_B();

  float sS[8], sQ[8];
#pragma unroll
  for (int ct = 0; ct < 8; ++ct) { sS[ct] = 0.f; sQ[ct] = 0.f; }

  for (int tile = blockIdx.x; tile < NTILE; tile += GGRID) {
    int rb = tile * 128 + wv * 16;
    f32x4 acc[8];
#pragma unroll
    for (int ct = 0; ct < 8; ++ct) acc[ct] = (f32x4){0.f, 0.f, 0.f, 0.f};
    GEMM_TILE_COMPUTE(rb);
#pragma unroll
    for (int ct = 0; ct < 8; ++ct) {
#pragma unroll
      for (int r = 0; r < 4; ++r) {
        float v = acc[ct][r];
        sS[ct] += v;
        sQ[ct] += v * v;
      }
    }
  }

  // block-level reduce through LDS (B no longer needed)
  __syncthreads();
  float* slds = (float*)blds;   // [8 waves][256] = 8KB
#pragma unroll
  for (int ct = 0; ct < 8; ++ct) {
    float s = sS[ct], q = sQ[ct];
    s += __shfl_xor(s, 16); q += __shfl_xor(q, 16);
    s += __shfl_xor(s, 32); q += __shfl_xor(q, 32);
    if (lane < 16) {
      slds[wv * 256 + ct * 16 + lane] = s;
      slds[wv * 256 + 128 + ct * 16 + lane] = q;
    }
  }
  __syncthreads();
  if (t < 256) {
    float a = 0.f;
#pragma unroll
    for (int w = 0; w < 8; ++w) a += slds[w * 256 + t];
    partials[blockIdx.x * 256 + t] = a;
  }
}

// ---- 9b. reduce partials; fold bias; emit sc / (bias*sc + shift) ---------
__global__ __launch_bounds__(1024) void k_stats(
    const float* __restrict__ partials, const float* __restrict__ bl,
    const float* __restrict__ gamma, const float* __restrict__ beta,
    float* __restrict__ ss)
{
  __shared__ float red[4][256];
  int t = threadIdx.x & 255, g = threadIdx.x >> 8;
  float a = 0.f;
#pragma unroll 8
  for (int blk = g; blk < GGRID; blk += 4) a += partials[blk * 256 + t];
  red[g][t] = a;
  __syncthreads();
  if (threadIdx.x < 256)
    red[0][t] = red[0][t] + red[1][t] + red[2][t] + red[3][t];
  __syncthreads();
  if (threadIdx.x < 128) {
    float Sr = red[0][t], Qr = red[0][128 + t];
    float b  = bl[t];
    float S  = Sr + (float)NN * b;                    // fold bias into stats
    float Q  = Qr + 2.f * b * Sr + (float)NN * b * b;
    float mu  = S / (float)NN;
    float var = Q / (float)NN - mu * mu;              // biased variance
    float rsig = rsqrtf(var + BN_EPS);
    float sc  = gamma[t] * rsig;
    float sh2 = beta[t] - mu * sc;
    ss[t]       = sc;
    ss[128 + t] = b * sc + sh2;                       // bias folded into shift
  }
}

// ---- 9c. GEMM pass 2: recompute + fused BN -> d_out ----------------------
__global__ __launch_bounds__(512, 2) void k_gemm2(
    const unsigned short* __restrict__ abuf,
    const unsigned short* __restrict__ wbf,
    const float* __restrict__ ss,
    float* __restrict__ out)
{
  __shared__ __align__(16) unsigned short blds[32768];
  const int t = threadIdx.x;
  const int lane = t & 63, wv = t >> 6;
  const int c15 = lane & 15, kg = lane >> 4;

  GEMM_STAGE_B();

  float sc[8], sh2[8];
#pragma unroll
  for (int ct = 0; ct < 8; ++ct) {
    sc[ct]  = ss[ct * 16 + c15];
    sh2[ct] = ss[128 + ct * 16 + c15];
  }

  for (int tile = blockIdx.x; tile < NTILE; tile += GGRID) {
    int rb = tile * 128 + wv * 16;
    f32x4 acc[8];
#pragma unroll
    for (int ct = 0; ct < 8; ++ct) acc[ct] = (f32x4){0.f, 0.f, 0.f, 0.f};
    GEMM_TILE_COMPUTE(rb);
    if (rb + 16 <= NN) {                 // wave-uniform: full strip
#pragma unroll
      for (int ct = 0; ct < 8; ++ct) {
        int col = ct * 16 + c15;
#pragma unroll
        for (int r = 0; r < 4; ++r) {
          long row = rb + kg * 4 + r;
          out[row * DD + col] = fmaf(acc[ct][r], sc[ct], sh2[ct]);
        }
      }
    } else {                             // last partial strip only
#pragma unroll
      for (int ct = 0; ct < 8; ++ct) {
        int col = ct * 16 + c15;
#pragma unroll
        for (int r = 0; r < 4; ++r) {
          long row = rb + kg * 4 + r;
          if (row < NN)
            out[row * DD + col] = fmaf(acc[ct][r], sc[ct], sh2[ct]);
        }
      }
    }
  }
}

extern "C" void kernel_launch(void* const* d_in, const int* in_sizes, int n_in,
                              void* d_out, int out_size, void* d_ws, size_t ws_size,
                              hipStream_t stream)
{
  const float* x     = (const float*)d_in[0];
  // d_in[1] = edge_attr — unused by the reference
  const float* Wl    = (const float*)d_in[2];
  const float* bl    = (const float*)d_in[3];
  const float* Wr    = (const float*)d_in[4];
  const float* gamma = (const float*)d_in[5];
  const float* beta  = (const float*)d_in[6];
  const int*   ei    = (const int*)d_in[7];
  float* out = (float*)d_out;

  char* ws = (char*)d_ws;
  unsigned short* abuf = (unsigned short*)(ws);            // 100096*256*2 = 51,249,152
  int*   esrc  = (int*)(ws + 51249152);                    //  2,560,000 -> 53,809,152
  int*   deg   = (int*)(ws + 53809152);                    //    400,384 -> 54,209,536
  int*   offs  = (int*)(ws + 54209536);                    //    400,384 -> 54,609,920
  int*   bsum  = (int*)(ws + 54609920);                    //      2,048 -> 54,611,968
  int*   boff  = (int*)(ws + 54611968);                    //      2,048 -> 54,614,016
  unsigned short* wbf = (unsigned short*)(ws + 54614016);  //     65,536 -> 54,679,552
  // dead-region reuse (stream-ordered):
  float* partials = (float*)esrc;   // gemm1 partials [512][256] f32; esrc dead after k_agg
  float* ssbuf    = (float*)deg;    // 256 f32; deg dead after k_fill
  (void)ws_size; (void)in_sizes; (void)n_in; (void)out_size;

  k_zero  <<<98,   1024, 0, stream>>>(deg);
  k_setup <<<SETUP_PREPX_BLOCKS + SETUP_PREPW_BLOCKS + SETUP_HIST_BLOCKS,
             256, 0, stream>>>(x, Wl, Wr, ei, abuf, wbf, deg);
  k_scan1 <<<NB,    256, 0, stream>>>(deg, bsum);
  k_scan2 <<<1,     512, 0, stream>>>(bsum, boff);
  k_scan3 <<<NB,    256, 0, stream>>>(deg, boff, offs);
  k_fill  <<<2500,  256, 0, stream>>>(ei, deg, esrc);
  k_agg   <<<25000, 256, 0, stream>>>(offs, esrc, abuf);
  k_gemm1 <<<GGRID, 512, 0, stream>>>(abuf, wbf, partials);
  k_stats <<<1,    1024, 0, stream>>>(partials, bl, gamma, beta, ssbuf);
  k_gemm2 <<<GGRID, 512, 0, stream>>>(abuf, wbf, ssbuf, out);
}

// Round 11
// 161.786 us; speedup vs baseline: 1.1143x; 1.1143x over previous
//
#include <hip/hip_runtime.h>
#include <stdint.h>

#define NN 100000     // nodes
#define NE 640000     // edges
#define DD 128        // features
#define BN_EPS 1e-5f
#define NB 391        // scan blocks: 391*256 = 100096 >= NN
#define NROWPAD 100096
#define NTILE 782     // 128-row tiles: 782*128 = 100096
#define GGRID 512     // gemm grid (2 blocks/CU)

// merged setup-kernel block ranges
#define SETUP_PREPX_BLOCKS 6256   // NROWPAD*16/256
#define SETUP_PREPW_BLOCKS 128
#define SETUP_HIST_BLOCKS  2500

typedef __attribute__((ext_vector_type(8)))  short bf16x8;
typedef __attribute__((ext_vector_type(4)))  float f32x4;

static __device__ __forceinline__ float bf2f(unsigned short s) {
  return __uint_as_float(((unsigned)s) << 16);
}
static __device__ __forceinline__ unsigned short f2bf(float f) {
  unsigned u = __float_as_uint(f);
  u += 0x7FFFu + ((u >> 16) & 1u);   // RNE
  return (unsigned short)(u >> 16);
}

// ---- 0. zero deg ---------------------------------------------------------
__global__ __launch_bounds__(1024) void k_zero(int* __restrict__ deg)
{
  int i = blockIdx.x * 1024 + threadIdx.x;
  if (i < NROWPAD) deg[i] = 0;
}

// ---- 1. merged setup: prepx (incl. pad-row zero) + prepw + hist ----------
__global__ __launch_bounds__(256) void k_setup(
    const float* __restrict__ x,
    const float* __restrict__ Wl, const float* __restrict__ Wr,
    const int* __restrict__ ei,
    unsigned short* __restrict__ abuf, unsigned short* __restrict__ wbf,
    int* __restrict__ deg)
{
  int b = blockIdx.x;
  if (b < SETUP_PREPX_BLOCKS) {
    // abuf[row][128+j] = bf16(relu(x[row][j])); pad rows zero BOTH halves
    int i = b * 256 + threadIdx.x;      // 0 .. NROWPAD*16-1
    int row = i >> 4, cj = i & 15;
    if (row < NN) {
      const float* xp = x + (long)row * DD + cj * 8;
      float tmp[8];
      *(float4*)(tmp)     = *(const float4*)(xp);
      *(float4*)(tmp + 4) = *(const float4*)(xp + 4);
      bf16x8 o;
#pragma unroll
      for (int e = 0; e < 8; ++e) o[e] = (short)f2bf(fmaxf(tmp[e], 0.f));
      *(bf16x8*)(abuf + (long)row * 256 + DD + cj * 8) = o;
    } else {                            // rows NN..NROWPAD-1: zero fill
      bf16x8 z = {};
      *(bf16x8*)(abuf + (long)row * 256 + cj * 8) = z;        // agg half
      *(bf16x8*)(abuf + (long)row * 256 + DD + cj * 8) = z;   // x half
    }
  } else if (b < SETUP_PREPX_BLOCKS + SETUP_PREPW_BLOCKS) {
    // wbf[col][0..255] = [Wl[col][:] | Wr[col][:]] as bf16
    int i = (b - SETUP_PREPX_BLOCKS) * 256 + threadIdx.x;
    int col = i >> 8, k = i & 255;
    float v = (k < DD) ? Wl[col * DD + k] : Wr[col * DD + (k - DD)];
    wbf[i] = f2bf(v);
  } else {
    // degree histogram
    int e = (b - SETUP_PREPX_BLOCKS - SETUP_PREPW_BLOCKS) * 256 + threadIdx.x;
    if (e < NE) atomicAdd(deg + ei[NE + e], 1);
  }
}

// ---- 4. block sums -------------------------------------------------------
__global__ __launch_bounds__(256) void k_scan1(const int* __restrict__ deg,
                                               int* __restrict__ bsum)
{
  __shared__ int sc[256];
  int t = threadIdx.x;
  sc[t] = deg[blockIdx.x * 256 + t];
  __syncthreads();
  for (int s = 128; s > 0; s >>= 1) {
    if (t < s) sc[t] += sc[t + s];
    __syncthreads();
  }
  if (t == 0) bsum[blockIdx.x] = sc[0];
}

// ---- 5. exclusive scan of block sums ------------------------------------
__global__ __launch_bounds__(512) void k_scan2(const int* __restrict__ bsum,
                                               int* __restrict__ boff)
{
  __shared__ int sc[512];
  int t = threadIdx.x;
  int v = (t < NB) ? bsum[t] : 0;
  sc[t] = v;
  __syncthreads();
  for (int s = 1; s < 512; s <<= 1) {
    int add = (t >= s) ? sc[t - s] : 0;
    __syncthreads();
    sc[t] += add;
    __syncthreads();
  }
  if (t < NB) boff[t] = sc[t] - v;
}

// ---- 6. per-element exclusive scan -> offs; deg becomes fill-cursor ------
__global__ __launch_bounds__(256) void k_scan3(int* __restrict__ deg,
                                               const int* __restrict__ boff,
                                               int* __restrict__ offs)
{
  __shared__ int sc[256];
  int t = threadIdx.x;
  int i = blockIdx.x * 256 + t;
  int v = deg[i];
  sc[t] = v;
  __syncthreads();
  for (int s = 1; s < 256; s <<= 1) {
    int add = (t >= s) ? sc[t - s] : 0;
    __syncthreads();
    sc[t] += add;
    __syncthreads();
  }
  int excl = sc[t] - v + boff[blockIdx.x];
  offs[i] = excl;
  deg[i]  = excl;
}

// ---- 7. fill CSR ---------------------------------------------------------
__global__ __launch_bounds__(256) void k_fill(const int* __restrict__ ei,
                                              int* __restrict__ cursor,
                                              int* __restrict__ esrc)
{
  int e = blockIdx.x * 256 + threadIdx.x;
  if (e >= NE) return;
  int pos = atomicAdd(cursor + ei[NE + e], 1);
  esrc[pos] = ei[e];
}

// ---- 8. gather-aggregate: abuf[dst][0..127] = bf16(mean(relu_x_bf16[src]))
// R10 REVERT to the R7 4x16 layout. R9's 8x8 layout tripled the per-node
// reduce tail (acc[16] x 3 shfl stages = 96 VALU/lane vs acc[8] x 2 = 32)
// and went VALU-bound (52% busy, +24us). 4 quarter-waves of 16 lanes own
// edge stream i*4+q; each lane reads bf16x8 (16B) -> one wave-wide load
// covers 4 DIFFERENT edges' rows (4x MLP; 8x with unroll 2). Lanes past
// the edge count hold src=NN (zeroed pad row) -> adds 0, branch-free.
// shfl_xor(16,32) reduce; quarter 0 packs+stores.
__global__ __launch_bounds__(256) void k_agg(const int* __restrict__ offs,
                                             const int* __restrict__ esrc,
                                             unsigned short* __restrict__ abuf)
{
  int dst = blockIdx.x * 4 + (threadIdx.x >> 6);
  if (dst >= NN) return;
  int lane = threadIdx.x & 63;
  int q  = lane >> 4;        // quarter-wave 0..3 = edge slot
  int fl = lane & 15;        // feature lane: feats fl*8 .. fl*8+7
  int off = offs[dst], end = offs[dst + 1];
  int deg = end - off;
  float acc[8];
#pragma unroll
  for (int e = 0; e < 8; ++e) acc[e] = 0.f;

  for (int base = off; base < end; base += 64) {
    int m = end - base; if (m > 64) m = 64;
    int mysrc = (base + lane < end) ? esrc[base + lane] : NN;  // NN = zero pad row
    int iters = (m + 3) >> 2;
#pragma unroll 2
    for (int i = 0; i < iters; ++i) {
      int src = __shfl(mysrc, i * 4 + q);    // i*4+q <= 63; >=m lanes hold NN
      bf16x8 w = *(const bf16x8*)(abuf + (long)src * 256 + DD + fl * 8);
#pragma unroll
      for (int e = 0; e < 8; ++e) acc[e] += bf2f((unsigned short)w[e]);
    }
  }

#pragma unroll
  for (int e = 0; e < 8; ++e) {
    acc[e] += __shfl_xor(acc[e], 16);
    acc[e] += __shfl_xor(acc[e], 32);
  }
  if (q == 0) {
    float rinv = (deg > 0) ? 1.0f / (float)deg : 0.f;
    bf16x8 o;
#pragma unroll
    for (int e = 0; e < 8; ++e) o[e] = (short)f2bf(acc[e] * rinv);
    *(bf16x8*)(abuf + (long)dst * 256 + fl * 8) = o;
  }
}

// ======== streaming GEMM core (barrier-free per wave) =====================
// Block: 512 thr = 8 waves. B (= wbf, 128x256 bf16 = 64KB) staged once in
// LDS with XOR-swizzle byte ^= (col&7)<<4. Each wave owns a 16-row strip
// per tile; A-fragments load DIRECTLY from global (wave-wide 16B load =
// 16 full 64B lines). No A-LDS, no barriers in the tile loop.
// REGISTER BUDGET: (512,2) caps VGPR at 128 (2 blocks/CU, LDS-bound).
// A-load unroll 4 (kept from R9: no spill signature, ~-8us on the pair).
#define GEMM_STAGE_B() \
  _Pragma("unroll") \
  for (int j = 0; j < 8; ++j) { \
    int id = j * 512 + t, col = id >> 5, seg = id & 31; \
    uint4 v = *(const uint4*)(wbf + col * 256 + seg * 8); \
    int byte = (col << 9) + (seg << 4); byte ^= (col & 7) << 4; \
    *(uint4*)((char*)blds + byte) = v; \
  } \
  __syncthreads();

#define GEMM_TILE_COMPUTE(rb) \
  { const unsigned short* ap = abuf + (long)((rb) + c15) * 256 + kg * 8; \
    _Pragma("unroll 4") \
    for (int ks = 0; ks < 8; ++ks) { \
      bf16x8 a = *(const bf16x8*)(ap + ks * 32); \
      _Pragma("unroll") \
      for (int ct = 0; ct < 8; ++ct) { \
        int byte = ((ct * 16 + c15) << 9) + (ks << 6) + (kg << 4); \
        byte ^= (c15 & 7) << 4; \
        bf16x8 b = *(const bf16x8*)((const char*)blds + byte); \
        acc[ct] = __builtin_amdgcn_mfma_f32_16x16x32_bf16(a, b, acc[ct], 0, 0, 0); \
      } \
    } }

// ---- 9a. GEMM pass 1: RAW column stats (no bias, no row guard) -----------
__global__ __launch_bounds__(512, 2) void k_gemm1(
    const unsigned short* __restrict__ abuf,
    const unsigned short* __restrict__ wbf,
    float* __restrict__ partials)
{
  __shared__ __align__(16) unsigned short blds[32768];   // 64KB B
  const int t = threadIdx.x;
  const int lane = t & 63, wv = t >> 6;
  const int c15 = lane & 15, kg = lane >> 4;

  GEMM_STAGE_B();

  float sS[8], sQ[8];
#pragma unroll
  for (int ct = 0; ct < 8; ++ct) { sS[ct] = 0.f; sQ[ct] = 0.f; }

  for (int tile = blockIdx.x; tile < NTILE; tile += GGRID) {
    int rb = tile * 128 + wv * 16;
    f32x4 acc[8];
#pragma unroll
    for (int ct = 0; ct < 8; ++ct) acc[ct] = (f32x4){0.f, 0.f, 0.f, 0.f};
    GEMM_TILE_COMPUTE(rb);
#pragma unroll
    for (int ct = 0; ct < 8; ++ct) {
#pragma unroll
      for (int r = 0; r < 4; ++r) {
        float v = acc[ct][r];
        sS[ct] += v;
        sQ[ct] += v * v;
      }
    }
  }

  // block-level reduce through LDS (B no longer needed)
  __syncthreads();
  float* slds = (float*)blds;   // [8 waves][256] = 8KB
#pragma unroll
  for (int ct = 0; ct < 8; ++ct) {
    float s = sS[ct], q = sQ[ct];
    s += __shfl_xor(s, 16); q += __shfl_xor(q, 16);
    s += __shfl_xor(s, 32); q += __shfl_xor(q, 32);
    if (lane < 16) {
      slds[wv * 256 + ct * 16 + lane] = s;
      slds[wv * 256 + 128 + ct * 16 + lane] = q;
    }
  }
  __syncthreads();
  if (t < 256) {
    float a = 0.f;
#pragma unroll
    for (int w = 0; w < 8; ++w) a += slds[w * 256 + t];
    partials[blockIdx.x * 256 + t] = a;
  }
}

// ---- 9b. reduce partials; fold bias; emit sc / (bias*sc + shift) ---------
__global__ __launch_bounds__(1024) void k_stats(
    const float* __restrict__ partials, const float* __restrict__ bl,
    const float* __restrict__ gamma, const float* __restrict__ beta,
    float* __restrict__ ss)
{
  __shared__ float red[4][256];
  int t = threadIdx.x & 255, g = threadIdx.x >> 8;
  float a = 0.f;
#pragma unroll 8
  for (int blk = g; blk < GGRID; blk += 4) a += partials[blk * 256 + t];
  red[g][t] = a;
  __syncthreads();
  if (threadIdx.x < 256)
    red[0][t] = red[0][t] + red[1][t] + red[2][t] + red[3][t];
  __syncthreads();
  if (threadIdx.x < 128) {
    float Sr = red[0][t], Qr = red[0][128 + t];
    float b  = bl[t];
    float S  = Sr + (float)NN * b;                    // fold bias into stats
    float Q  = Qr + 2.f * b * Sr + (float)NN * b * b;
    float mu  = S / (float)NN;
    float var = Q / (float)NN - mu * mu;              // biased variance
    float rsig = rsqrtf(var + BN_EPS);
    float sc  = gamma[t] * rsig;
    float sh2 = beta[t] - mu * sc;
    ss[t]       = sc;
    ss[128 + t] = b * sc + sh2;                       // bias folded into shift
  }
}

// ---- 9c. GEMM pass 2: recompute + fused BN -> d_out ----------------------
__global__ __launch_bounds__(512, 2) void k_gemm2(
    const unsigned short* __restrict__ abuf,
    const unsigned short* __restrict__ wbf,
    const float* __restrict__ ss,
    float* __restrict__ out)
{
  __shared__ __align__(16) unsigned short blds[32768];
  const int t = threadIdx.x;
  const int lane = t & 63, wv = t >> 6;
  const int c15 = lane & 15, kg = lane >> 4;

  GEMM_STAGE_B();

  float sc[8], sh2[8];
#pragma unroll
  for (int ct = 0; ct < 8; ++ct) {
    sc[ct]  = ss[ct * 16 + c15];
    sh2[ct] = ss[128 + ct * 16 + c15];
  }

  for (int tile = blockIdx.x; tile < NTILE; tile += GGRID) {
    int rb = tile * 128 + wv * 16;
    f32x4 acc[8];
#pragma unroll
    for (int ct = 0; ct < 8; ++ct) acc[ct] = (f32x4){0.f, 0.f, 0.f, 0.f};
    GEMM_TILE_COMPUTE(rb);
    if (rb + 16 <= NN) {                 // wave-uniform: full strip
#pragma unroll
      for (int ct = 0; ct < 8; ++ct) {
        int col = ct * 16 + c15;
#pragma unroll
        for (int r = 0; r < 4; ++r) {
          long row = rb + kg * 4 + r;
          out[row * DD + col] = fmaf(acc[ct][r], sc[ct], sh2[ct]);
        }
      }
    } else {                             // last partial strip only
#pragma unroll
      for (int ct = 0; ct < 8; ++ct) {
        int col = ct * 16 + c15;
#pragma unroll
        for (int r = 0; r < 4; ++r) {
          long row = rb + kg * 4 + r;
          if (row < NN)
            out[row * DD + col] = fmaf(acc[ct][r], sc[ct], sh2[ct]);
        }
      }
    }
  }
}

extern "C" void kernel_launch(void* const* d_in, const int* in_sizes, int n_in,
                              void* d_out, int out_size, void* d_ws, size_t ws_size,
                              hipStream_t stream)
{
  const float* x     = (const float*)d_in[0];
  // d_in[1] = edge_attr — unused by the reference
  const float* Wl    = (const float*)d_in[2];
  const float* bl    = (const float*)d_in[3];
  const float* Wr    = (const float*)d_in[4];
  const float* gamma = (const float*)d_in[5];
  const float* beta  = (const float*)d_in[6];
  const int*   ei    = (const int*)d_in[7];
  float* out = (float*)d_out;

  char* ws = (char*)d_ws;
  unsigned short* abuf = (unsigned short*)(ws);            // 100096*256*2 = 51,249,152
  int*   esrc  = (int*)(ws + 51249152);                    //  2,560,000 -> 53,809,152
  int*   deg   = (int*)(ws + 53809152);                    //    400,384 -> 54,209,536
  int*   offs  = (int*)(ws + 54209536);                    //    400,384 -> 54,609,920
  int*   bsum  = (int*)(ws + 54609920);                    //      2,048 -> 54,611,968
  int*   boff  = (int*)(ws + 54611968);                    //      2,048 -> 54,614,016
  unsigned short* wbf = (unsigned short*)(ws + 54614016);  //     65,536 -> 54,679,552
  // dead-region reuse (stream-ordered):
  float* partials = (float*)esrc;   // gemm1 partials [512][256] f32; esrc dead after k_agg
  float* ssbuf    = (float*)deg;    // 256 f32; deg dead after k_fill
  (void)ws_size; (void)in_sizes; (void)n_in; (void)out_size;

  k_zero  <<<98,   1024, 0, stream>>>(deg);
  k_setup <<<SETUP_PREPX_BLOCKS + SETUP_PREPW_BLOCKS + SETUP_HIST_BLOCKS,
             256, 0, stream>>>(x, Wl, Wr, ei, abuf, wbf, deg);
  k_scan1 <<<NB,    256, 0, stream>>>(deg, bsum);
  k_scan2 <<<1,     512, 0, stream>>>(bsum, boff);
  k_scan3 <<<NB,    256, 0, stream>>>(deg, boff, offs);
  k_fill  <<<2500,  256, 0, stream>>>(ei, deg, esrc);
  k_agg   <<<25000, 256, 0, stream>>>(offs, esrc, abuf);
  k_gemm1 <<<GGRID, 512, 0, stream>>>(abuf, wbf, partials);
  k_stats <<<1,    1024, 0, stream>>>(partials, bl, gamma, beta, ssbuf);
  k_gemm2 <<<GGRID, 512, 0, stream>>>(abuf, wbf, ssbuf, out);
}